// Round 3
// baseline (59.652 us; speedup 1.0000x reference)
//
#include <hip/hip_runtime.h>
#include <math.h>

// ASD between two 16384x3 fp32 point sets. fp32-VALU compute-bound (no fp32
// MFMA on CDNA4; bf16 numerically insufficient at coords~128; no packed-f32
// double-rate on gfx950 -- spec 157.3 TF = 1 fma/lane/cyc).
//
// R1: LDS-pipe-bound at QPT=2 -> QPT=8 broadcast amortization.
// R2: 46 us @ 2 waves/SIMD = 59% issue efficiency; VALU accepts 1 wave64
//     instr / 2 cyc / SIMD, so 2 waves/SIMD has zero stall slack.
// R3: NCHUNK 32->64 -> 1024 blocks = 4 blocks/CU = 4 waves/SIMD (2x issue
//     slack), CHUNK=256 (4 KB LDS), unroll 8.
//
// Inner loop: t = fma(qz2,rz, fma(qy2,ry, fma(qx2,rx, r2))); m = min(m,t)
// -> 4 VALU per pair. Floor: 537M pairs * 4 / 64 lanes * 2cyc / 1024 SIMD
// = 27 us at 2.4 GHz.

#define NPTS    16384
#define THREADS 256
#define QPT     8                    // queries per thread
#define QBLK    (THREADS * QPT)      // 2048 queries per block
#define NQB     (NPTS / QBLK)        // 8 query-blocks per direction
#define NCHUNK  64
#define CHUNK   (NPTS / NCHUNK)      // 256 refs per chunk

__global__ __launch_bounds__(THREADS) void asd_min_kernel(
    const float* __restrict__ real_pts,
    const float* __restrict__ pred_pts,
    unsigned int* __restrict__ ws)
{
    const int bid   = blockIdx.x;          // 1024 blocks: 2 dirs x 8 qb x 64 chunks
    const int dir   = bid >> 9;
    const int rem   = bid & 511;
    const int chunk = rem >> 3;            // 0..63
    const int qb    = rem & 7;             // 0..7

    // dir 0: pred -> real ; dir 1: real -> pred
    const float* __restrict__ qpts = dir ? real_pts : pred_pts;
    const float* __restrict__ rpts = dir ? pred_pts : real_pts;

    __shared__ float4 sref[CHUNK];         // {x,y,z,r2}: 4 KB

    const int tid = threadIdx.x;

    const int rbase = chunk * CHUNK;
    for (int i = tid; i < CHUNK; i += THREADS) {
        const float rx = rpts[(rbase + i) * 3 + 0];
        const float ry = rpts[(rbase + i) * 3 + 1];
        const float rz = rpts[(rbase + i) * 3 + 2];
        sref[i] = make_float4(rx, ry, rz, fmaf(rx, rx, fmaf(ry, ry, rz * rz)));
    }

    // Query registers: pre-scaled by -2 so the inner loop is pure fma.
    float qx2[QPT], qy2[QPT], qz2[QPT], q2[QPT], m[QPT];
    const int q0 = qb * QBLK + tid;
#pragma unroll
    for (int k = 0; k < QPT; ++k) {
        const int qi = q0 + k * THREADS;
        const float x = qpts[qi * 3 + 0];
        const float y = qpts[qi * 3 + 1];
        const float z = qpts[qi * 3 + 2];
        qx2[k] = -2.0f * x;
        qy2[k] = -2.0f * y;
        qz2[k] = -2.0f * z;
        q2[k]  = fmaf(x, x, fmaf(y, y, z * z));
        m[k]   = INFINITY;                 // min over r of (r2 - 2 q.r)
    }

    __syncthreads();

#pragma unroll 8
    for (int r = 0; r < CHUNK; ++r) {
        const float4 rv = sref[r];         // broadcast read: 1 per 512 pairs
#pragma unroll
        for (int k = 0; k < QPT; ++k) {
            float t = fmaf(qx2[k], rv.x, rv.w);
            t = fmaf(qy2[k], rv.y, t);
            t = fmaf(qz2[k], rv.z, t);
            m[k] = fminf(m[k], t);         // 3 fma + 1 min per pair
        }
    }

#pragma unroll
    for (int k = 0; k < QPT; ++k) {
        const int qi = q0 + k * THREADS;
        const float d2 = fmaxf(m[k] + q2[k], 0.0f);   // clamp (matches ref; also
                                                      // keeps uint-order valid)
        atomicMin(&ws[dir * NPTS + qi], __float_as_uint(d2));
    }
}

__global__ __launch_bounds__(1024) void asd_reduce_kernel(
    const unsigned int* __restrict__ ws, float* __restrict__ out)
{
    const int tid = threadIdx.x;
    float s = 0.0f;

    for (int q = tid; q < 2 * NPTS; q += 1024)
        s += sqrtf(__uint_as_float(ws[q]));

    __shared__ float red[16];
#pragma unroll
    for (int off = 32; off > 0; off >>= 1)
        s += __shfl_down(s, off, 64);
    const int wave = tid >> 6;
    const int lane = tid & 63;
    if (lane == 0) red[wave] = s;
    __syncthreads();
    if (tid < 16) {
        float v = red[tid];
#pragma unroll
        for (int off = 8; off > 0; off >>= 1)
            v += __shfl_down(v, off, 16);
        if (tid == 0) out[0] = v / (float)(2 * NPTS);
    }
}

extern "C" void kernel_launch(void* const* d_in, const int* in_sizes, int n_in,
                              void* d_out, int out_size, void* d_ws, size_t ws_size,
                              hipStream_t stream)
{
    const float* real_pts = (const float*)d_in[0];
    const float* pred_pts = (const float*)d_in[1];
    float* out = (float*)d_out;
    unsigned int* ws = (unsigned int*)d_ws;    // 2*16384 uints = 128 KiB

    // Init per-query running mins to a huge float (0x7F7F7F7F = 3.39e38).
    hipMemsetAsync(ws, 0x7F, 2 * NPTS * sizeof(unsigned int), stream);

    asd_min_kernel<<<2 * NQB * NCHUNK, THREADS, 0, stream>>>(real_pts, pred_pts, ws);
    asd_reduce_kernel<<<1, 1024, 0, stream>>>(ws, out);
}